// Round 1
// baseline (737.322 us; speedup 1.0000x reference)
//
#include <hip/hip_runtime.h>

// ---------------------------------------------------------------------------
// TypeSpecificProjection: out[v] = feat[v, :d_t] @ W_t + b_t,  t = type_ids[v]
// Strategy: bucket vertices by type (count/prefix/scatter), pre-swizzle W into
// MFMA fragment layout (bf16), then ONE fused exact-grid GEMM kernel covering
// all 4 types. Operand-swapped MFMA (W as A-operand) makes D = (X*W)^T so the
// epilogue is direct f32x4 stores — no LDS transpose, no epilogue barriers.
// ---------------------------------------------------------------------------

typedef __attribute__((ext_vector_type(8))) __bf16 bf16x8;
typedef __attribute__((ext_vector_type(4))) __bf16 bf16x4;
typedef __attribute__((ext_vector_type(4))) float f32x4;

// ws layout (bytes):
//      0: counts[4]
//     16: cursors[4]
//     32: bases[4]
//     48: tilebase[5]           (tile prefix sums, bytes 48..67)
//    128: idx[500000]           (2,000,000 B, ends at 2,000,128)
// 2000128: wbuf bf16[81920]     (163,840 B)   total ~2.07 MiB
#define WS_WBUF_BYTES 2000128

// ---------------------------------------------------------------------------
// Fused prep: blocks [0,320) swizzle weights, blocks [320,809) count types.
__global__ void prep_kernel(const int* __restrict__ types, int n,
                            int* __restrict__ counts,
                            const float* __restrict__ W0, const float* __restrict__ W1,
                            const float* __restrict__ W2, const float* __restrict__ W3,
                            __bf16* __restrict__ wbuf) {
    if (blockIdx.x < 320) {
        // Pre-swizzle all 4 weight matrices into MFMA fragment order (bf16):
        // element (t, c, nt, lane, j) <- W_t[c*32 + (lane>>4)*8 + j][nt*16 + (lane&15)]
        int o = blockIdx.x * 256 + threadIdx.x;
        const int woff[5] = {0, 16384, 49152, 73728, 81920};
        int t = 0;
        while (o >= woff[t + 1]) ++t;
        int rel = o - woff[t];
        int j    = rel & 7;
        int lane = (rel >> 3) & 63;
        int cb   = rel >> 9;          // (c*16 + nt)
        int c    = cb >> 4;
        int nt   = cb & 15;
        int k = c * 32 + (lane >> 4) * 8 + j;
        int nn = nt * 16 + (lane & 15);
        const float* W = (t == 0) ? W0 : (t == 1) ? W1 : (t == 2) ? W2 : W3;
        wbuf[o] = (__bf16)W[k * 256 + nn];
    } else {
        __shared__ int h[4];
        if (threadIdx.x < 4) h[threadIdx.x] = 0;
        __syncthreads();
        for (int i = (int)(blockIdx.x - 320) * 256 + threadIdx.x; i < n;
             i += 489 * 256)
            atomicAdd(&h[types[i]], 1);
        __syncthreads();
        if (threadIdx.x < 4) atomicAdd(&counts[threadIdx.x], h[threadIdx.x]);
    }
}

__global__ void bases_kernel(const int* __restrict__ counts,
                             int* __restrict__ bases, int* __restrict__ cursors,
                             int* __restrict__ tb) {
    if (threadIdx.x == 0) {
        int s = 0, ts = 0;
        for (int t = 0; t < 4; ++t) {
            bases[t] = s; cursors[t] = s; tb[t] = ts;
            s += counts[t];
            ts += (counts[t] + 63) >> 6;
        }
        tb[4] = ts;
    }
}

// Block-aggregated scatter: 4 global atomics per block instead of 1 per thread.
__global__ void scatter_kernel(const int* __restrict__ types, int n,
                               int* __restrict__ cursors, int* __restrict__ idx) {
    __shared__ int h[4], hb[4], cur[4];
    const int tid = threadIdx.x;
    if (tid < 4) h[tid] = 0;
    __syncthreads();
    const int i0 = blockIdx.x * 1024;
    int myt[4];
    #pragma unroll
    for (int k = 0; k < 4; ++k) {
        int i = i0 + k * 256 + tid;
        myt[k] = (i < n) ? types[i] : -1;
        if (myt[k] >= 0) atomicAdd(&h[myt[k]], 1);
    }
    __syncthreads();
    if (tid < 4) { hb[tid] = atomicAdd(&cursors[tid], h[tid]); cur[tid] = 0; }
    __syncthreads();
    #pragma unroll
    for (int k = 0; k < 4; ++k) {
        if (myt[k] >= 0) {
            int p = atomicAdd(&cur[myt[k]], 1);
            idx[hb[myt[k]] + p] = i0 + k * 256 + tid;
        }
    }
}

// ---------------------------------------------------------------------------
// GEMM body per type: M = 64 gathered rows, N = 256, K = d_t.
// Block: 256 threads (4 waves). Wave w owns output cols [w*64, w*64+64).
// A staged fp32->bf16 in LDS (row stride K+8 to break bank conflicts);
// W read as coalesced 16B frags straight from the swizzled L2-resident wbuf.
// MFMA operands SWAPPED: D = W^T_tile * X_tile, so C/D layout gives each lane
// 4 consecutive out-columns of one vertex -> direct f32x4 stores, no epilogue
// LDS transpose, no epilogue barriers.
// ---------------------------------------------------------------------------
template <int K, int WOFF>
__device__ __forceinline__ void gemm_body(const float* __restrict__ feat,
                                          const int* __restrict__ idxbuf,
                                          int base, int m0, int mcount,
                                          const __bf16* __restrict__ wbuf,
                                          const float* __restrict__ bias,
                                          float* __restrict__ out,
                                          __bf16* ldsA, int* lidx) {
    constexpr int LDA = K + 8;                // bf16 elements; +8 kills conflicts
    const int tid = threadIdx.x;

    if (tid < 64) lidx[tid] = (tid < mcount) ? idxbuf[base + m0 + tid] : 0;
    __syncthreads();

    // Stage A tile: gather rows, fp32 -> bf16.
    constexpr int K4 = K / 4;                 // float4 per row
    for (int f = tid; f < 64 * K4; f += 256) {
        int row = f / K4;                     // compile-time divisor
        int c4  = f - row * K4;
        if (row < mcount) {
            int g = lidx[row];
            f32x4 v = *reinterpret_cast<const f32x4*>(&feat[(size_t)g * 128 + c4 * 4]);
            bf16x4 h = {(__bf16)v.x, (__bf16)v.y, (__bf16)v.z, (__bf16)v.w};
            *reinterpret_cast<bf16x4*>(&ldsA[row * LDA + c4 * 4]) = h;
        }
    }
    __syncthreads();

    const int lane = tid & 63;
    const int wave = tid >> 6;
    const int m = lane & 15;                  // vertex within 16-group (N of mfma)
    const int q = lane >> 4;

    f32x4 acc[4][4] = {};
    const __bf16* __restrict__ wb = wbuf + WOFF;

    #pragma unroll
    for (int c = 0; c < K / 32; ++c) {
        bf16x8 a[4];
        #pragma unroll
        for (int mi = 0; mi < 4; ++mi)
            a[mi] = *reinterpret_cast<const bf16x8*>(
                        &ldsA[(mi * 16 + m) * LDA + c * 32 + q * 8]);
        #pragma unroll
        for (int ni = 0; ni < 4; ++ni) {
            int nt = wave * 4 + ni;
            bf16x8 b = *reinterpret_cast<const bf16x8*>(
                           wb + ((size_t)(c * 16 + nt) * 64 + lane) * 8);
            // Swapped operands: A-op = W frag (same swizzle layout), B-op = X.
            // D[row=out-col local][col=vertex local].
            #pragma unroll
            for (int mi = 0; mi < 4; ++mi)
                acc[mi][ni] = __builtin_amdgcn_mfma_f32_16x16x32_bf16(
                                  b, a[mi], acc[mi][ni], 0, 0, 0);
        }
    }

    // Epilogue: lane holds out[v = mi*16+m][wave*64 + ni*16 + q*4 + r], r=0..3.
    f32x4 biasv[4];
    #pragma unroll
    for (int ni = 0; ni < 4; ++ni)
        biasv[ni] = *reinterpret_cast<const f32x4*>(&bias[wave * 64 + ni * 16 + q * 4]);
    #pragma unroll
    for (int mi = 0; mi < 4; ++mi) {
        int v = mi * 16 + m;
        if (v < mcount) {
            size_t ro = (size_t)lidx[v] * 256 + wave * 64 + q * 4;
            #pragma unroll
            for (int ni = 0; ni < 4; ++ni) {
                f32x4 r = acc[mi][ni] + biasv[ni];
                *reinterpret_cast<f32x4*>(&out[ro + ni * 16]) = r;
            }
        }
    }
}

// One fused launch, exact tile grid: block -> (type, m0) via tile prefix sums.
__launch_bounds__(256, 3)
__global__ void gemm_all(const float* __restrict__ feat,
                         const int* __restrict__ ws_i,
                         const __bf16* __restrict__ wbuf,
                         const float* __restrict__ b0, const float* __restrict__ b1,
                         const float* __restrict__ b2, const float* __restrict__ b3,
                         float* __restrict__ out) {
    __shared__ __bf16 ldsA[64 * 136];         // max K=128 -> LDA=136
    __shared__ int lidx[64];

    const int* tb = ws_i + 12;                // tilebase[5] at byte 48
    const int blk = blockIdx.x;
    if (blk >= tb[4]) return;
    const int t = (blk >= tb[2]) ? ((blk >= tb[3]) ? 3 : 2)
                                 : ((blk >= tb[1]) ? 1 : 0);
    const int m0     = (blk - tb[t]) * 64;
    const int mcount = min(64, ws_i[t] - m0); // counts at int offset 0
    const int base   = ws_i[8 + t];           // bases at byte 32
    const int* idxbuf = ws_i + 32;            // idx at byte 128

    switch (t) {
        case 0: gemm_body< 64,     0>(feat, idxbuf, base, m0, mcount, wbuf, b0, out, ldsA, lidx); break;
        case 1: gemm_body<128, 16384>(feat, idxbuf, base, m0, mcount, wbuf, b1, out, ldsA, lidx); break;
        case 2: gemm_body< 96, 49152>(feat, idxbuf, base, m0, mcount, wbuf, b2, out, ldsA, lidx); break;
        case 3: gemm_body< 32, 73728>(feat, idxbuf, base, m0, mcount, wbuf, b3, out, ldsA, lidx); break;
    }
}

// ---------------------------------------------------------------------------
extern "C" void kernel_launch(void* const* d_in, const int* in_sizes, int n_in,
                              void* d_out, int out_size, void* d_ws, size_t ws_size,
                              hipStream_t stream) {
    const float* feat  = (const float*)d_in[0];
    const int*   types = (const int*)d_in[1];
    const float* W0 = (const float*)d_in[2];
    const float* b0 = (const float*)d_in[3];
    const float* W1 = (const float*)d_in[4];
    const float* b1 = (const float*)d_in[5];
    const float* W2 = (const float*)d_in[6];
    const float* b2 = (const float*)d_in[7];
    const float* W3 = (const float*)d_in[8];
    const float* b3 = (const float*)d_in[9];
    float* out = (float*)d_out;
    const int n = in_sizes[0] / 128;   // 500000 vertices

    char* ws = (char*)d_ws;
    int* ws_i    = (int*)ws;
    int* counts  = ws_i;           // byte 0
    int* cursors = ws_i + 4;       // byte 16
    int* bases   = ws_i + 8;       // byte 32
    int* tb      = ws_i + 12;      // byte 48 (5 ints)
    int* idx     = ws_i + 32;      // byte 128
    __bf16* wbuf = (__bf16*)(ws + WS_WBUF_BYTES);

    hipMemsetAsync(counts, 0, 48, stream);
    prep_kernel<<<809, 256, 0, stream>>>(types, n, counts, W0, W1, W2, W3, wbuf);
    bases_kernel<<<1, 64, 0, stream>>>(counts, bases, cursors, tb);
    scatter_kernel<<<(n + 1023) / 1024, 256, 0, stream>>>(types, n, cursors, idx);

    const int tiles = (n + 63) / 64 + 4;   // >= sum of per-type tile counts
    gemm_all<<<tiles, 256, 0, stream>>>(feat, ws_i, wbuf, b0, b1, b2, b3, out);
}